// Round 7
// baseline (183.543 us; speedup 1.0000x reference)
//
#include <hip/hip_runtime.h>
#include <hip/hip_bf16.h>
#include <math.h>

#define EMBED 1024
#define HDIM  64
#define BATCH 4
#define SEQ   2048

typedef __attribute__((ext_vector_type(8))) short short8;
typedef __attribute__((ext_vector_type(4))) float f32x4;
typedef unsigned int u32;
typedef unsigned short u16;

static __device__ __forceinline__ u16 f2bf(float f) {
    union { float f; u32 u; } v; v.f = f;
    u32 r = v.u + 0x7fffu + ((v.u >> 16) & 1u);  // round-to-nearest-even
    return (u16)(r >> 16);
}

// async global->LDS, 16B per lane. LDS dest must equal uniform_base + lane*16.
static __device__ __forceinline__ void gload_lds16(const u16* g, u16* l) {
    __builtin_amdgcn_global_load_lds(
        (const __attribute__((address_space(1))) u32*)g,
        (__attribute__((address_space(3))) u32*)l, 16, 0, 0);
}

// ---------------------------------------------------------------------------
// K0: WqT[d][e] = bf16(Wq[e][d]), WkT likewise. Also zeroes lsum (8192 f32).
// grid (16,2) x 256.
// ---------------------------------------------------------------------------
__global__ __launch_bounds__(256) void wt_kernel(
    const float* __restrict__ Wq, const float* __restrict__ Wk,
    u16* __restrict__ WqT, u16* __restrict__ WkT, float* __restrict__ lsum)
{
    __shared__ float tile[64][65];
    const float* W = blockIdx.y ? Wk : Wq;
    u16* WT = blockIdx.y ? WkT : WqT;
    int e0 = blockIdx.x * 64;
    int t = threadIdx.x, c = t & 63, r4 = t >> 6;
    lsum[(blockIdx.y * 16 + blockIdx.x) * 256 + t] = 0.f;   // covers 8192
    for (int r = r4; r < 64; r += 4)
        tile[r][c] = W[(size_t)(e0 + r) * HDIM + c];   // tile[e-e0][d]
    __syncthreads();
    for (int d = r4; d < 64; d += 4)
        WT[(size_t)d * EMBED + e0 + c] = f2bf(tile[c][d]);
}

// ---------------------------------------------------------------------------
// K1: proj only. Q = 0.125*(h*Wq+bq), K = h*Wk+bk. grid 512 x 256.
// Double-buffered LDS; h prefetched depth-2, W-frags 1 iter ahead.
// ---------------------------------------------------------------------------
__global__ __launch_bounds__(256) void proj_kernel(
    const float* __restrict__ h, const u16* __restrict__ WqT, const u16* __restrict__ WkT,
    const float* __restrict__ bq, const float* __restrict__ bk,
    u16* __restrict__ Qbf, u16* __restrict__ Kbf)
{
    __shared__ u16 hs[2][16][136];   // 128 + 8 pad
    int b = blockIdx.x >> 7, s0 = (blockIdx.x & 127) * 16;
    int t = threadIdx.x, lane = t & 63, w = t >> 6;
    int l15 = lane & 15, quad = lane >> 4;
    int pj = w >> 1, nh = (w & 1) * 32;
    const float* hb = h + ((size_t)b * SEQ + s0) * EMBED;
    const u16* Wp = pj ? WkT : WqT;
    int r = t >> 4, c4 = (t & 15) * 4;

    f32x4 preA0 = *(const f32x4*)(hb + (size_t)r * EMBED + c4);
    f32x4 preA1 = *(const f32x4*)(hb + (size_t)r * EMBED + 64 + c4);
    f32x4 preB0 = *(const f32x4*)(hb + (size_t)r * EMBED + 128 + c4);
    f32x4 preB1 = *(const f32x4*)(hb + (size_t)r * EMBED + 192 + c4);
    f32x4 accA[2], accB[2];
    accA[0] = accA[1] = accB[0] = accB[1] = (f32x4){0.f, 0.f, 0.f, 0.f};

    const u16* Wrow0 = Wp + (size_t)(nh + l15) * EMBED;
    const u16* Wrow1 = Wp + (size_t)(nh + 16 + l15) * EMBED;

    short8 cw[8];
#pragma unroll
    for (int i = 0; i < 4; i++) {
        cw[i]     = *(const short8*)(Wrow0 + i * 32 + quad * 8);
        cw[4 + i] = *(const short8*)(Wrow1 + i * 32 + quad * 8);
    }

    for (int it = 0; it < 8; ++it) {
        int ec = it * 128, buf = it & 1;
        uint2 pk;
        pk.x = (u32)f2bf(preA0[0]) | ((u32)f2bf(preA0[1]) << 16);
        pk.y = (u32)f2bf(preA0[2]) | ((u32)f2bf(preA0[3]) << 16);
        *(uint2*)&hs[buf][r][c4] = pk;
        pk.x = (u32)f2bf(preA1[0]) | ((u32)f2bf(preA1[1]) << 16);
        pk.y = (u32)f2bf(preA1[2]) | ((u32)f2bf(preA1[3]) << 16);
        *(uint2*)&hs[buf][r][64 + c4] = pk;
        __syncthreads();

        preA0 = preB0; preA1 = preB1;
        if (it + 2 < 8) {
            preB0 = *(const f32x4*)(hb + (size_t)r * EMBED + ec + 256 + c4);
            preB1 = *(const f32x4*)(hb + (size_t)r * EMBED + ec + 320 + c4);
        }
        short8 nw[8];
#pragma unroll
        for (int i = 0; i < 8; i++) nw[i] = cw[i];
        if (it + 1 < 8) {
#pragma unroll
            for (int i = 0; i < 4; i++) {
                nw[i]     = *(const short8*)(Wrow0 + ec + 128 + i * 32 + quad * 8);
                nw[4 + i] = *(const short8*)(Wrow1 + ec + 128 + i * 32 + quad * 8);
            }
        }

        short8 a0 = *(const short8*)&hs[buf][l15][quad * 8];
        short8 a1 = *(const short8*)&hs[buf][l15][32 + quad * 8];
        short8 a2 = *(const short8*)&hs[buf][l15][64 + quad * 8];
        short8 a3 = *(const short8*)&hs[buf][l15][96 + quad * 8];
        accA[0] = __builtin_amdgcn_mfma_f32_16x16x32_bf16(a0, cw[0], accA[0], 0, 0, 0);
        accA[1] = __builtin_amdgcn_mfma_f32_16x16x32_bf16(a0, cw[4], accA[1], 0, 0, 0);
        accB[0] = __builtin_amdgcn_mfma_f32_16x16x32_bf16(a1, cw[1], accB[0], 0, 0, 0);
        accB[1] = __builtin_amdgcn_mfma_f32_16x16x32_bf16(a1, cw[5], accB[1], 0, 0, 0);
        accA[0] = __builtin_amdgcn_mfma_f32_16x16x32_bf16(a2, cw[2], accA[0], 0, 0, 0);
        accA[1] = __builtin_amdgcn_mfma_f32_16x16x32_bf16(a2, cw[6], accA[1], 0, 0, 0);
        accB[0] = __builtin_amdgcn_mfma_f32_16x16x32_bf16(a3, cw[3], accB[0], 0, 0, 0);
        accB[1] = __builtin_amdgcn_mfma_f32_16x16x32_bf16(a3, cw[7], accB[1], 0, 0, 0);
#pragma unroll
        for (int i = 0; i < 8; i++) cw[i] = nw[i];
    }

    const float* bias = pj ? bk : bq;
    float scale = pj ? 1.0f : 0.125f;
    u16* outp = pj ? Kbf : Qbf;
    float bv0 = bias[nh + l15], bv1 = bias[nh + 16 + l15];
#pragma unroll
    for (int rr = 0; rr < 4; rr++) {
        size_t row = (size_t)b * SEQ + s0 + quad * 4 + rr;
        outp[row * HDIM + nh + l15]      = f2bf((accA[0][rr] + accB[0][rr] + bv0) * scale);
        outp[row * HDIM + nh + 16 + l15] = f2bf((accA[1][rr] + accB[1][rr] + bv1) * scale);
    }
}

// ---------------------------------------------------------------------------
// K2: lse only -- lsum[b][k] = sum_q exp(S[q,k]). sw V3 minus the Wmat
// stores (32 MB of writes gone; the exp(S) values are recomputed in the
// fused kernel from identical bf16 inputs => bit-identical S).
// grid (S/64, 4, B) x 512; partial sums via atomicAdd (8 adds/address).
// ---------------------------------------------------------------------------
__global__ __launch_bounds__(512) void lse_kernel(
    const u16* __restrict__ Qbf, const u16* __restrict__ Kbf,
    float* __restrict__ lsum)
{
    int b = blockIdx.z;
    int k0 = blockIdx.x * 64;
    int t = threadIdx.x, lane = t & 63, w = t >> 6;
    int l15 = lane & 15, quad = lane >> 4;
    const u16* Qb = Qbf + (size_t)b * SEQ * HDIM;
    const u16* Kb = Kbf + (size_t)b * SEQ * HDIM;

    short8 kfr[4][2];
#pragma unroll
    for (int g = 0; g < 4; g++)
#pragma unroll
        for (int hh = 0; hh < 2; hh++)
            kfr[g][hh] = *(const short8*)(
                Kb + (size_t)(k0 + g * 16 + l15) * HDIM + hh * 32 + quad * 8);

    f32x4 lacc[4];
#pragma unroll
    for (int g = 0; g < 4; g++) lacc[g] = (f32x4){0.f, 0.f, 0.f, 0.f};

    int qs = (blockIdx.y * 8 + w) * 64;   // wave owns 64 q

#pragma unroll
    for (int half = 0; half < 2; ++half) {
        int q0 = qs + half * 32;
        short8 cf[2][2];
#pragma unroll
        for (int a = 0; a < 2; a++)
#pragma unroll
            for (int hh = 0; hh < 2; hh++)
                cf[a][hh] = *(const short8*)(
                    Qb + (size_t)(q0 + a * 16 + l15) * HDIM + hh * 32 + quad * 8);

        f32x4 acc[2][4];
#pragma unroll
        for (int a = 0; a < 2; a++)
#pragma unroll
            for (int g = 0; g < 4; g++) acc[a][g] = (f32x4){0.f, 0.f, 0.f, 0.f};
#pragma unroll
        for (int a = 0; a < 2; a++)
#pragma unroll
            for (int g = 0; g < 4; g++) {
                acc[a][g] = __builtin_amdgcn_mfma_f32_16x16x32_bf16(
                    kfr[g][0], cf[a][0], acc[a][g], 0, 0, 0);
                acc[a][g] = __builtin_amdgcn_mfma_f32_16x16x32_bf16(
                    kfr[g][1], cf[a][1], acc[a][g], 0, 0, 0);
            }
#pragma unroll
        for (int a = 0; a < 2; a++)
#pragma unroll
            for (int g = 0; g < 4; g++) {
                lacc[g][0] += __expf(acc[a][g][0]);
                lacc[g][1] += __expf(acc[a][g][1]);
                lacc[g][2] += __expf(acc[a][g][2]);
                lacc[g][3] += __expf(acc[a][g][3]);
            }
    }
#pragma unroll
    for (int m = 1; m <= 8; m <<= 1)
#pragma unroll
        for (int g = 0; g < 4; g++) {
            lacc[g][0] += __shfl_xor(lacc[g][0], m, 64);
            lacc[g][1] += __shfl_xor(lacc[g][1], m, 64);
            lacc[g][2] += __shfl_xor(lacc[g][2], m, 64);
            lacc[g][3] += __shfl_xor(lacc[g][3], m, 64);
        }
    if (l15 == 0) {
        float* lp = lsum + b * SEQ + k0 + quad * 4;
#pragma unroll
        for (int g = 0; g < 4; g++) {
            atomicAdd(lp + g * 16 + 0, lacc[g][0]);
            atomicAdd(lp + g * 16 + 1, lacc[g][1]);
            atomicAdd(lp + g * 16 + 2, lacc[g][2]);
            atomicAdd(lp + g * 16 + 3, lacc[g][3]);
        }
    }
}

// ---------------------------------------------------------------------------
// K3: transpose + scale: hT[b][e][s] = bf16( h[b][s][e] * rcp(lsum[b][s]) ).
// grid (S/64, E/64, B) x 256.
// ---------------------------------------------------------------------------
__global__ __launch_bounds__(256) void tscale_kernel(
    const float* __restrict__ h, const float* __restrict__ lsum,
    u16* __restrict__ hT)
{
    __shared__ float tile[64][65];
    int b  = blockIdx.z;
    int s0 = blockIdx.x * 64, e0 = blockIdx.y * 64;
    int t = threadIdx.x;
    int r16 = t >> 4, c4 = (t & 15) * 4;
    const float* hb = h + (size_t)b * SEQ * EMBED;
#pragma unroll
    for (int rr = r16; rr < 64; rr += 16) {
        f32x4 v = *(const f32x4*)(hb + (size_t)(s0 + rr) * EMBED + e0 + c4);
        *(f32x4*)&tile[rr][c4] = v;
    }
    __syncthreads();
    f32x4 ls = *(const f32x4*)(lsum + b * SEQ + s0 + c4);
    f32x4 il4;
    il4[0] = __builtin_amdgcn_rcpf(ls[0]);
    il4[1] = __builtin_amdgcn_rcpf(ls[1]);
    il4[2] = __builtin_amdgcn_rcpf(ls[2]);
    il4[3] = __builtin_amdgcn_rcpf(ls[3]);
    u16* hTb = hT + (size_t)b * EMBED * SEQ;
#pragma unroll
    for (int er = r16; er < 64; er += 16) {
        u16 p0 = f2bf(tile[c4 + 0][er] * il4[0]);
        u16 p1 = f2bf(tile[c4 + 1][er] * il4[1]);
        u16 p2 = f2bf(tile[c4 + 2][er] * il4[2]);
        u16 p3 = f2bf(tile[c4 + 3][er] * il4[3]);
        uint2 pk;
        pk.x = (u32)p0 | ((u32)p1 << 16);
        pk.y = (u32)p2 | ((u32)p3 << 16);
        *(uint2*)(hTb + (size_t)(e0 + er) * SEQ + s0 + c4) = pk;
    }
}

// ---------------------------------------------------------------------------
// K4 FUSED: out[b][q][e] = sum_k bf16(exp(S[q,k])) * hT[b][e][k]
// Eliminates the 32MB Wmat write + 32MB re-read: S is recomputed per
// e-panel (x4 redundancy = +25% MFMA; floor 17.2us) and exp(S)->bf16 goes
// through a 16KB P_lds instead of HBM.
// Block: q-tile 128 x e-tile 256, 512 thr = 8 waves. grid (16,4,4) = 256
// blocks = 1/CU. Per k-tile (64 k):
//  S phase: kfr 2 ds_read (K from ring) -> 8 S-MFMA (Q-frags in regs,
//    loop-invariant) -> 16 exp -> 4 ds_write_b64 to P_lds (swizzled) ||
//    stage tile kt+2 (5 gload_lds16: hT 4 + K 1) -> lgkm0 -> barrier
//  PV phase: per kstep {4 af (P_lds) + 4 bfr (hT ring) ds_read_b128 ->
//    lgkm0 -> setprio -> 16 MFMA} x2 -> vmcnt(5) -> barrier
// 3-slot ring (hT 32KB + K 8KB = 40KB/slot), depth-2 staging, counted
// vmcnt(5) never 0 until kt=30. S div: wave=(kgrp=w&3, qh=w>>2);
// PV div: wave owns q-half (qh) x e-64-group (en=w&3); acc[4][4].
// Swizzle: phys chunk = logical ^ (row&7) -- gload side pre-swizzled
// global source + linear dest; P written AND read with same XOR.
// ---------------------------------------------------------------------------
__global__ __launch_bounds__(512, 2) void fused_kernel(
    const u16* __restrict__ Qbf, const u16* __restrict__ Kbf,
    const u16* __restrict__ hT, float* __restrict__ out)
{
    // 3 x (hT 32KB + K 8KB) = 122880 B ring, then P_lds 16KB. Total 136KB.
    __shared__ __align__(16) char smem[3 * 40960 + 16384];
    int b = blockIdx.z;
    int q0 = blockIdx.x * 128, e0 = blockIdx.y * 256;
    int t = threadIdx.x, lane = t & 63, w = t >> 6;
    int l15 = lane & 15, quad = lane >> 4;
    const u16* Qb  = Qbf + (size_t)b * SEQ * HDIM;
    const u16* Kb  = Kbf + (size_t)b * SEQ * HDIM;
    const u16* hTb = hT + (size_t)b * EMBED * SEQ;
    int kgrp = w & 3, qh = w >> 2;   // S-phase division
    int en = w & 3;                  // PV e-group (q-half = qh)

    f32x4 acc[4][4];
#pragma unroll
    for (int i = 0; i < 4; i++)
#pragma unroll
        for (int j = 0; j < 4; j++) acc[i][j] = (f32x4){0.f, 0.f, 0.f, 0.f};

    // ---- Q fragments: loop-invariant, register-resident (32 VGPR).
    short8 qf[4][2];
#pragma unroll
    for (int a = 0; a < 4; a++)
#pragma unroll
        for (int dh = 0; dh < 2; dh++)
            qf[a][dh] = *(const short8*)(
                Qb + (size_t)(q0 + qh * 64 + a * 16 + l15) * HDIM + dh * 32 + quad * 8);

    // ---- hoisted LDS offsets
    int offK[2];                      // K-frag reads (slot-rel; K at +32768)
#pragma unroll
    for (int dh = 0; dh < 2; dh++) {
        int kr = kgrp * 16 + l15;
        int c  = (dh * 4 + quad) ^ (kr & 7);
        offK[dh] = 32768 + kr * 128 + c * 16;
    }
    int offPw[4];                     // P writes (abs; P at 122880)
#pragma unroll
    for (int a = 0; a < 4; a++) {
        int row = qh * 64 + a * 16 + l15;
        int c   = (kgrp * 2 + (quad >> 1)) ^ (row & 7);
        offPw[a] = 122880 + row * 128 + c * 16 + (quad & 1) * 8;
    }
    int offPA[2][4];                  // P reads (abs)
#pragma unroll
    for (int ks = 0; ks < 2; ks++)
#pragma unroll
        for (int i = 0; i < 4; i++) {
            int row = qh * 64 + i * 16 + l15;
            int c   = (ks * 4 + quad) ^ (row & 7);
            offPA[ks][i] = 122880 + row * 128 + c * 16;
        }
    int offBT[2][4];                  // hT reads (slot-rel)
#pragma unroll
    for (int ks = 0; ks < 2; ks++)
#pragma unroll
        for (int j = 0; j < 4; j++) {
            int row = en * 64 + j * 16 + l15;
            int c   = (ks * 4 + quad) ^ (row & 7);
            offBT[ks][j] = row * 128 + c * 16;
        }

    // ---- staging: pre-swizzled global sources + linear LDS dests
    const u16* gH[4]; const u16* gK1;
    int dH[4], dK;
#pragma unroll
    for (int ld = 0; ld < 4; ld++) {
        int rowb = w * 32 + ld * 8;
        int row  = rowb + (lane >> 3);
        int cg   = (lane & 7) ^ (row & 7);
        gH[ld] = hTb + (size_t)(e0 + row) * SEQ + cg * 8;
        dH[ld] = rowb * 128 + lane * 16;
    }
    {
        int rowb = w * 8;
        int row  = rowb + (lane >> 3);
        int cg   = (lane & 7) ^ (row & 7);
        gK1 = Kb + (size_t)row * HDIM + cg * 8;
        dK  = 32768 + rowb * 128 + lane * 16;
    }

#define STAGE(si)                                                              \
    {                                                                          \
        gload_lds16(gH[0], (u16*)(smem + (si) * 40960 + dH[0]));               \
        gload_lds16(gH[1], (u16*)(smem + (si) * 40960 + dH[1]));               \
        gload_lds16(gH[2], (u16*)(smem + (si) * 40960 + dH[2]));               \
        gload_lds16(gH[3], (u16*)(smem + (si) * 40960 + dH[3]));               \
        gload_lds16(gK1,   (u16*)(smem + (si) * 40960 + dK));                  \
    }
#define ADV()                                                                  \
    {                                                                          \
        gH[0] += 64; gH[1] += 64; gH[2] += 64; gH[3] += 64;                    \
        gK1 += 64 * HDIM;                                                      \
    }

#define TILE(si, si2, DO_STAGE, VMC)                                           \
    {                                                                          \
        char* Sb = smem + (si) * 40960;                                        \
        /* ---- S phase ---- */                                                \
        short8 kfr0 = *(const short8*)(Sb + offK[0]);                          \
        short8 kfr1 = *(const short8*)(Sb + offK[1]);                          \
        f32x4 sA[4];                                                           \
        _Pragma("unroll")                                                      \
        for (int a = 0; a < 4; a++)                                            \
            sA[a] = __builtin_amdgcn_mfma_f32_16x16x32_bf16(                   \
                kfr0, qf[a][0], (f32x4){0.f, 0.f, 0.f, 0.f}, 0, 0, 0);         \
        _Pragma("unroll")                                                      \
        for (int a = 0; a < 4; a++)                                            \
            sA[a] = __builtin_amdgcn_mfma_f32_16x16x32_bf16(                   \
                kfr1, qf[a][1], sA[a], 0, 0, 0);                               \
        _Pragma("unroll")                                                      \
        for (int a = 0; a < 4; a++) {                                          \
            float x0 = __expf(sA[a][0]), x1 = __expf(sA[a][1]);                \
            float x2 = __expf(sA[a][2]), x3 = __expf(sA[a][3]);                \
            uint2 pk;                                                          \
            pk.x = (u32)f2bf(x0) | ((u32)f2bf(x1) << 16);                      \
            pk.y = (u32)f2bf(x2) | ((u32)f2bf(x3) << 16);                      \
            *(uint2*)(smem + offPw[a]) = pk;                                   \
        }                                                                      \
        if (DO_STAGE) { STAGE(si2) ADV() }                                     \
        asm volatile("s_waitcnt lgkmcnt(0)" ::: "memory");                     \
        __builtin_amdgcn_sched_barrier(0);                                     \
        __builtin_amdgcn_s_barrier();                                          \
        /* ---- PV phase ---- */                                               \
        short8 paf[4], pbf[4];                                                 \
        _Pragma("unroll")                                                      \
        for (int i = 0; i < 4; i++)                                            \
            paf[i] = *(const short8*)(smem + offPA[0][i]);                     \
        _Pragma("unroll")                                                      \
        for (int j = 0; j < 4; j++)                                            \
            pbf[j] = *(const short8*)(Sb + offBT[0][j]);                       \
        asm volatile("s_waitcnt lgkmcnt(0)" ::: "memory");                     \
        __builtin_amdgcn_sched_barrier(0);                                     \
        __builtin_amdgcn_s_setprio(1);                                         \
        _Pragma("unroll")                                                      \
        for (int i = 0; i < 4; i++)                                            \
            _Pragma("unroll")                                                  \
            for (int j = 0; j < 4; j++)                                        \
                acc[i][j] = __builtin_amdgcn_mfma_f32_16x16x32_bf16(           \
                    paf[i], pbf[j], acc[i][j], 0, 0, 0);                       \
        __builtin_amdgcn_s_setprio(0);                                         \
        _Pragma("unroll")                                                      \
        for (int i = 0; i < 4; i++)                                            \
            paf[i] = *(const short8*)(smem + offPA[1][i]);                     \
        _Pragma("unroll")                                                      \
        for (int j = 0; j < 4; j++)                                            \
            pbf[j] = *(const short8*)(Sb + offBT[1][j]);                       \
        asm volatile("s_waitcnt lgkmcnt(0)" ::: "memory");                     \
        __builtin_amdgcn_sched_barrier(0);                                     \
        __builtin_amdgcn_s_setprio(1);                                         \
        _Pragma("unroll")                                                      \
        for (int i = 0; i < 4; i++)                                            \
            _Pragma("unroll")                                                  \
            for (int j = 0; j < 4; j++)                                        \
                acc[i][j] = __builtin_amdgcn_mfma_f32_16x16x32_bf16(           \
                    paf[i], pbf[j], acc[i][j], 0, 0, 0);                       \
        __builtin_amdgcn_s_setprio(0);                                         \
        if ((VMC) == 5) { asm volatile("s_waitcnt vmcnt(5)" ::: "memory"); }   \
        else if ((VMC) == 0) { asm volatile("s_waitcnt vmcnt(0)" ::: "memory"); } \
        __builtin_amdgcn_s_barrier();                                          \
    }

    // Prologue: drain qf loads so counted vmcnt sees only staging; stage
    // tiles 0,1; wait own tile-0 loads; publish.
    asm volatile("s_waitcnt vmcnt(0)" ::: "memory");
    STAGE(0) ADV()
    STAGE(1) ADV()
    asm volatile("s_waitcnt vmcnt(5)" ::: "memory");
    __builtin_amdgcn_s_barrier();

    // Tiles 0..29 (staging 2..31, vmcnt(5) each), then 30 (drain), 31.
    for (int g = 0; g < 10; ++g) {
        TILE(0, 2, true, 5)
        TILE(1, 0, true, 5)
        TILE(2, 1, true, 5)
    }
    TILE(0, 2, false, 0)
    TILE(1, 0, false, -1)
#undef TILE
#undef STAGE
#undef ADV

    // Epilogue: wave owns q[qh*64 +: 64] x e[en*64 +: 64]; direct f32 store.
    float* outb = out + (size_t)b * SEQ * EMBED;
#pragma unroll
    for (int i = 0; i < 4; i++)
#pragma unroll
        for (int j = 0; j < 4; j++)
#pragma unroll
            for (int r = 0; r < 4; r++)
                outb[(size_t)(q0 + qh * 64 + i * 16 + quad * 4 + r) * EMBED
                     + e0 + en * 64 + j * 16 + l15] = acc[i][j][r];
}

// ---------------------------------------------------------------------------
extern "C" void kernel_launch(void* const* d_in, const int* in_sizes, int n_in,
                              void* d_out, int out_size, void* d_ws, size_t ws_size,
                              hipStream_t stream) {
    (void)in_sizes; (void)n_in; (void)out_size; (void)ws_size;
    const float* h  = (const float*)d_in[0];
    const float* Wq = (const float*)d_in[1];
    const float* bq = (const float*)d_in[2];
    const float* Wk = (const float*)d_in[3];
    const float* bk = (const float*)d_in[4];
    // d_in[5], d_in[6] (Wv, bv) are dead in the reference.
    float* out = (float*)d_out;

    char* ws = (char*)d_ws;
    u16*   Qbf  = (u16*)(ws);                                  // 1 MB
    u16*   Kbf  = (u16*)(ws + (1ull << 20));                   // 1 MB
    u16*   hT   = (u16*)(ws + (2ull << 20));                   // 16 MB
    float* lsum = (float*)(ws + (18ull << 20));                // 32 KB

    hipLaunchKernelGGL(wt_kernel, dim3(16, 2), dim3(256), 0, stream,
                       Wq, Wk, (u16*)(ws + (18ull << 20) + (128ull << 10)),
                       (u16*)(ws + (18ull << 20) + (256ull << 10)), lsum);
    hipLaunchKernelGGL(proj_kernel, dim3(512), dim3(256), 0, stream,
                       h, (const u16*)(ws + (18ull << 20) + (128ull << 10)),
                       (const u16*)(ws + (18ull << 20) + (256ull << 10)),
                       bq, bk, Qbf, Kbf);
    hipLaunchKernelGGL(lse_kernel, dim3(32, 4, 4), dim3(512), 0, stream,
                       Qbf, Kbf, lsum);
    hipLaunchKernelGGL(tscale_kernel, dim3(32, 16, 4), dim3(256), 0, stream,
                       h, lsum, hT);
    hipLaunchKernelGGL(fused_kernel, dim3(16, 4, 4), dim3(512), 0, stream,
                       Qbf, Kbf, hT, out);
}

// Round 8
// 173.521 us; speedup vs baseline: 1.0578x; 1.0578x over previous
//
#include <hip/hip_runtime.h>
#include <hip/hip_bf16.h>
#include <math.h>

#define EMBED 1024
#define HDIM  64
#define BATCH 4
#define SEQ   2048

typedef __attribute__((ext_vector_type(8))) short short8;
typedef __attribute__((ext_vector_type(4))) float f32x4;
typedef unsigned int u32;
typedef unsigned short u16;

static __device__ __forceinline__ u16 f2bf(float f) {
    union { float f; u32 u; } v; v.f = f;
    u32 r = v.u + 0x7fffu + ((v.u >> 16) & 1u);  // round-to-nearest-even
    return (u16)(r >> 16);
}

// async global->LDS, 16B per lane. LDS dest must equal uniform_base + lane*16.
static __device__ __forceinline__ void gload_lds16(const u16* g, u16* l) {
    __builtin_amdgcn_global_load_lds(
        (const __attribute__((address_space(1))) u32*)g,
        (__attribute__((address_space(3))) u32*)l, 16, 0, 0);
}

// ---------------------------------------------------------------------------
// K0: WqT[d][e] = bf16(Wq[e][d]), WkT likewise. Also zeroes lsum (8192 f32,
// one store per thread) -- must happen every iteration (ws is re-poisoned).
// grid (16,2) x 256.
// ---------------------------------------------------------------------------
__global__ __launch_bounds__(256) void wt_kernel(
    const float* __restrict__ Wq, const float* __restrict__ Wk,
    u16* __restrict__ WqT, u16* __restrict__ WkT, float* __restrict__ lsum)
{
    __shared__ float tile[64][65];
    const float* W = blockIdx.y ? Wk : Wq;
    u16* WT = blockIdx.y ? WkT : WqT;
    int e0 = blockIdx.x * 64;
    int t = threadIdx.x, c = t & 63, r4 = t >> 6;
    lsum[(blockIdx.y * 16 + blockIdx.x) * 256 + t] = 0.f;   // covers 8192
    for (int r = r4; r < 64; r += 4)
        tile[r][c] = W[(size_t)(e0 + r) * HDIM + c];   // tile[e-e0][d]
    __syncthreads();
    for (int d = r4; d < 64; d += 4)
        WT[(size_t)d * EMBED + e0 + c] = f2bf(tile[c][d]);
}

// ---------------------------------------------------------------------------
// K1: proj only. Q = 0.125*(h*Wq+bq), K = h*Wk+bk. grid 512 x 256.
// Double-buffered LDS; h prefetched depth-2, W-frags 1 iter ahead.
// ---------------------------------------------------------------------------
__global__ __launch_bounds__(256) void proj_kernel(
    const float* __restrict__ h, const u16* __restrict__ WqT, const u16* __restrict__ WkT,
    const float* __restrict__ bq, const float* __restrict__ bk,
    u16* __restrict__ Qbf, u16* __restrict__ Kbf)
{
    __shared__ u16 hs[2][16][136];   // 128 + 8 pad
    int b = blockIdx.x >> 7, s0 = (blockIdx.x & 127) * 16;
    int t = threadIdx.x, lane = t & 63, w = t >> 6;
    int l15 = lane & 15, quad = lane >> 4;
    int pj = w >> 1, nh = (w & 1) * 32;
    const float* hb = h + ((size_t)b * SEQ + s0) * EMBED;
    const u16* Wp = pj ? WkT : WqT;
    int r = t >> 4, c4 = (t & 15) * 4;

    f32x4 preA0 = *(const f32x4*)(hb + (size_t)r * EMBED + c4);
    f32x4 preA1 = *(const f32x4*)(hb + (size_t)r * EMBED + 64 + c4);
    f32x4 preB0 = *(const f32x4*)(hb + (size_t)r * EMBED + 128 + c4);
    f32x4 preB1 = *(const f32x4*)(hb + (size_t)r * EMBED + 192 + c4);
    f32x4 accA[2], accB[2];
    accA[0] = accA[1] = accB[0] = accB[1] = (f32x4){0.f, 0.f, 0.f, 0.f};

    const u16* Wrow0 = Wp + (size_t)(nh + l15) * EMBED;
    const u16* Wrow1 = Wp + (size_t)(nh + 16 + l15) * EMBED;

    short8 cw[8];
#pragma unroll
    for (int i = 0; i < 4; i++) {
        cw[i]     = *(const short8*)(Wrow0 + i * 32 + quad * 8);
        cw[4 + i] = *(const short8*)(Wrow1 + i * 32 + quad * 8);
    }

    for (int it = 0; it < 8; ++it) {
        int ec = it * 128, buf = it & 1;
        uint2 pk;
        pk.x = (u32)f2bf(preA0[0]) | ((u32)f2bf(preA0[1]) << 16);
        pk.y = (u32)f2bf(preA0[2]) | ((u32)f2bf(preA0[3]) << 16);
        *(uint2*)&hs[buf][r][c4] = pk;
        pk.x = (u32)f2bf(preA1[0]) | ((u32)f2bf(preA1[1]) << 16);
        pk.y = (u32)f2bf(preA1[2]) | ((u32)f2bf(preA1[3]) << 16);
        *(uint2*)&hs[buf][r][64 + c4] = pk;
        __syncthreads();

        preA0 = preB0; preA1 = preB1;
        if (it + 2 < 8) {
            preB0 = *(const f32x4*)(hb + (size_t)r * EMBED + ec + 256 + c4);
            preB1 = *(const f32x4*)(hb + (size_t)r * EMBED + ec + 320 + c4);
        }
        short8 nw[8];
#pragma unroll
        for (int i = 0; i < 8; i++) nw[i] = cw[i];
        if (it + 1 < 8) {
#pragma unroll
            for (int i = 0; i < 4; i++) {
                nw[i]     = *(const short8*)(Wrow0 + ec + 128 + i * 32 + quad * 8);
                nw[4 + i] = *(const short8*)(Wrow1 + ec + 128 + i * 32 + quad * 8);
            }
        }

        short8 a0 = *(const short8*)&hs[buf][l15][quad * 8];
        short8 a1 = *(const short8*)&hs[buf][l15][32 + quad * 8];
        short8 a2 = *(const short8*)&hs[buf][l15][64 + quad * 8];
        short8 a3 = *(const short8*)&hs[buf][l15][96 + quad * 8];
        accA[0] = __builtin_amdgcn_mfma_f32_16x16x32_bf16(a0, cw[0], accA[0], 0, 0, 0);
        accA[1] = __builtin_amdgcn_mfma_f32_16x16x32_bf16(a0, cw[4], accA[1], 0, 0, 0);
        accB[0] = __builtin_amdgcn_mfma_f32_16x16x32_bf16(a1, cw[1], accB[0], 0, 0, 0);
        accB[1] = __builtin_amdgcn_mfma_f32_16x16x32_bf16(a1, cw[5], accB[1], 0, 0, 0);
        accA[0] = __builtin_amdgcn_mfma_f32_16x16x32_bf16(a2, cw[2], accA[0], 0, 0, 0);
        accA[1] = __builtin_amdgcn_mfma_f32_16x16x32_bf16(a2, cw[6], accA[1], 0, 0, 0);
        accB[0] = __builtin_amdgcn_mfma_f32_16x16x32_bf16(a3, cw[3], accB[0], 0, 0, 0);
        accB[1] = __builtin_amdgcn_mfma_f32_16x16x32_bf16(a3, cw[7], accB[1], 0, 0, 0);
#pragma unroll
        for (int i = 0; i < 8; i++) cw[i] = nw[i];
    }

    const float* bias = pj ? bk : bq;
    float scale = pj ? 1.0f : 0.125f;
    u16* outp = pj ? Kbf : Qbf;
    float bv0 = bias[nh + l15], bv1 = bias[nh + 16 + l15];
#pragma unroll
    for (int rr = 0; rr < 4; rr++) {
        size_t row = (size_t)b * SEQ + s0 + quad * 4 + rr;
        outp[row * HDIM + nh + l15]      = f2bf((accA[0][rr] + accB[0][rr] + bv0) * scale);
        outp[row * HDIM + nh + 16 + l15] = f2bf((accA[1][rr] + accB[1][rr] + bv1) * scale);
    }
}

// ---------------------------------------------------------------------------
// K2 V3 (reverted from R7 fused -- pre-registered failure branch hit):
// coalesced-line sw at full occupancy. Block owns 64 CONTIGUOUS k x 512 q
// (q split over 4 blocks). grid (S/64, 4, B) = 512 blocks x 512 thr.
// Wave owns 64 q. Column sums PARTIAL per block -> atomicAdd into lsum
// (zeroed by wt; 8 adds/address). tscale computes invl = rcp(lsum).
// ---------------------------------------------------------------------------
__global__ __launch_bounds__(512) void sw_kernel(
    const u16* __restrict__ Qbf, const u16* __restrict__ Kbf,
    u16* __restrict__ Wmat, float* __restrict__ lsum)
{
    int b = blockIdx.z;
    int k0 = blockIdx.x * 64;
    int t = threadIdx.x, lane = t & 63, w = t >> 6;
    int l15 = lane & 15, quad = lane >> 4;
    const u16* Qb = Qbf + (size_t)b * SEQ * HDIM;
    const u16* Kb = Kbf + (size_t)b * SEQ * HDIM;
    u16* Wb = Wmat + (size_t)b * SEQ * SEQ;

    short8 kfr[4][2];
#pragma unroll
    for (int g = 0; g < 4; g++)
#pragma unroll
        for (int hh = 0; hh < 2; hh++)
            kfr[g][hh] = *(const short8*)(
                Kb + (size_t)(k0 + g * 16 + l15) * HDIM + hh * 32 + quad * 8);

    f32x4 lacc[4];
#pragma unroll
    for (int g = 0; g < 4; g++) lacc[g] = (f32x4){0.f, 0.f, 0.f, 0.f};

    int qs = (blockIdx.y * 8 + w) * 64;   // wave owns 64 q

#pragma unroll
    for (int half = 0; half < 2; ++half) {
        int q0 = qs + half * 32;
        short8 cf[2][2];
#pragma unroll
        for (int a = 0; a < 2; a++)
#pragma unroll
            for (int hh = 0; hh < 2; hh++)
                cf[a][hh] = *(const short8*)(
                    Qb + (size_t)(q0 + a * 16 + l15) * HDIM + hh * 32 + quad * 8);

        // A = K rows (m=k), B = Q rows (n=q):
        // acc[a][g][r] = S[q0 + a*16 + l15][k0 + g*16 + quad*4 + r]
        f32x4 acc[2][4];
#pragma unroll
        for (int a = 0; a < 2; a++)
#pragma unroll
            for (int g = 0; g < 4; g++) acc[a][g] = (f32x4){0.f, 0.f, 0.f, 0.f};
#pragma unroll
        for (int a = 0; a < 2; a++)
#pragma unroll
            for (int g = 0; g < 4; g++) {
                acc[a][g] = __builtin_amdgcn_mfma_f32_16x16x32_bf16(
                    kfr[g][0], cf[a][0], acc[a][g], 0, 0, 0);
                acc[a][g] = __builtin_amdgcn_mfma_f32_16x16x32_bf16(
                    kfr[g][1], cf[a][1], acc[a][g], 0, 0, 0);
            }
#pragma unroll
        for (int a = 0; a < 2; a++) {
            u16* wrow = Wb + (size_t)(q0 + a * 16 + l15) * SEQ + k0;
#pragma unroll
            for (int g = 0; g < 4; g++) {
                float e0 = __expf(acc[a][g][0]), e1 = __expf(acc[a][g][1]);
                float e2 = __expf(acc[a][g][2]), e3 = __expf(acc[a][g][3]);
                lacc[g][0] += e0; lacc[g][1] += e1;
                lacc[g][2] += e2; lacc[g][3] += e3;
                uint2 pk;
                pk.x = (u32)f2bf(e0) | ((u32)f2bf(e1) << 16);
                pk.y = (u32)f2bf(e2) | ((u32)f2bf(e3) << 16);
                *(uint2*)(wrow + g * 16 + quad * 4) = pk;
            }
        }
    }
#pragma unroll
    for (int m = 1; m <= 8; m <<= 1)
#pragma unroll
        for (int g = 0; g < 4; g++) {
            lacc[g][0] += __shfl_xor(lacc[g][0], m, 64);
            lacc[g][1] += __shfl_xor(lacc[g][1], m, 64);
            lacc[g][2] += __shfl_xor(lacc[g][2], m, 64);
            lacc[g][3] += __shfl_xor(lacc[g][3], m, 64);
        }
    if (l15 == 0) {
        float* lp = lsum + b * SEQ + k0 + quad * 4;
#pragma unroll
        for (int g = 0; g < 4; g++) {
            atomicAdd(lp + g * 16 + 0, lacc[g][0]);
            atomicAdd(lp + g * 16 + 1, lacc[g][1]);
            atomicAdd(lp + g * 16 + 2, lacc[g][2]);
            atomicAdd(lp + g * 16 + 3, lacc[g][3]);
        }
    }
}

// ---------------------------------------------------------------------------
// K3: transpose + scale: hT[b][e][s] = bf16( h[b][s][e] * rcp(lsum[b][s]) ).
// grid (S/64, E/64, B) x 256.
// ---------------------------------------------------------------------------
__global__ __launch_bounds__(256) void tscale_kernel(
    const float* __restrict__ h, const float* __restrict__ lsum,
    u16* __restrict__ hT)
{
    __shared__ float tile[64][65];
    int b  = blockIdx.z;
    int s0 = blockIdx.x * 64, e0 = blockIdx.y * 64;
    int t = threadIdx.x;
    int r16 = t >> 4, c4 = (t & 15) * 4;
    const float* hb = h + (size_t)b * SEQ * EMBED;
#pragma unroll
    for (int rr = r16; rr < 64; rr += 16) {
        f32x4 v = *(const f32x4*)(hb + (size_t)(s0 + rr) * EMBED + e0 + c4);
        *(f32x4*)&tile[rr][c4] = v;
    }
    __syncthreads();
    f32x4 ls = *(const f32x4*)(lsum + b * SEQ + s0 + c4);
    f32x4 il4;
    il4[0] = __builtin_amdgcn_rcpf(ls[0]);
    il4[1] = __builtin_amdgcn_rcpf(ls[1]);
    il4[2] = __builtin_amdgcn_rcpf(ls[2]);
    il4[3] = __builtin_amdgcn_rcpf(ls[3]);
    u16* hTb = hT + (size_t)b * EMBED * SEQ;
#pragma unroll
    for (int er = r16; er < 64; er += 16) {
        u16 p0 = f2bf(tile[c4 + 0][er] * il4[0]);
        u16 p1 = f2bf(tile[c4 + 1][er] * il4[1]);
        u16 p2 = f2bf(tile[c4 + 2][er] * il4[2]);
        u16 p3 = f2bf(tile[c4 + 3][er] * il4[3]);
        uint2 pk;
        pk.x = (u32)p0 | ((u32)p1 << 16);
        pk.y = (u32)p2 | ((u32)p3 << 16);
        *(uint2*)(hTb + (size_t)(e0 + er) * SEQ + s0 + c4) = pk;
    }
}

// ---------------------------------------------------------------------------
// K4: out[b][q][e] = sum_k Wmat[b][q][k] * hT[b][e][k]
// V6 = V5 (frozen schedule) + XCD WORKING-SET REMAP. Default dispatch put
// XCD = q-panel: each XCD's 32 resident blocks touch 4MB Wmat + ALL 16MB hT
// vs 4MB L2 -> thrash (FETCH 82MB vs 48 compulsory). Remap (1D grid 256,
// XCD = bid%8 on round-robin dispatch): c=bid&7, j=bid>>3;
//   x = ((c&1)<<2)|(j>>3), y = j&7, z = c>>1
// -> per XCD: z fixed, 4 q-panels, 8 e-panels: working set = 4MB Wmat +
// 4MB hT[z] (2.5x smaller); hT[z] shared by only 2 XCDs (L3-friendly).
// Bijective; schedule/geometry byte-identical to V5.
// BM=256 x BN=128, BK=64, 512 thr = 8 waves (2 kf x 2M x 2N; wave tile
// 128x64 over its 32-wide k-half; acc[8][4]). 3-slot LDS ring (144KB),
// depth-2 staging, vmcnt(6) counted, never 0 until kt=30.
// ---------------------------------------------------------------------------
__global__ __launch_bounds__(512, 2) void out_gemm_kernel(
    const u16* __restrict__ Wmat, const u16* __restrict__ hT, float* __restrict__ out)
{
    __shared__ __align__(16) char smem[3 * 49152];   // 3 x (A 32KB + B 16KB)
    int bid = blockIdx.x;
    int c = bid & 7, j = bid >> 3;
    int px = ((c & 1) << 2) | (j >> 3);   // q-panel 0..7
    int py = j & 7;                       // e-panel 0..7
    int b  = c >> 1;                      // batch 0..3
    int q0 = px * 256, e0 = py * 128;
    int t = threadIdx.x, lane = t & 63, w = t >> 6;
    int l15 = lane & 15, quad = lane >> 4;
    const u16* Wb  = Wmat + (size_t)b * SEQ * SEQ;
    const u16* hTb = hT + (size_t)b * EMBED * SEQ;
    int kf = w >> 2;                 // k-half group (0: k 0..31, 1: k 32..63)
    int wm = (w >> 1) & 1, wn = w & 1;
    int wq = wm * 128, we = wn * 64; // wave tile origin (128 x 64)

    f32x4 acc[8][4];
#pragma unroll
    for (int i = 0; i < 8; i++)
#pragma unroll
        for (int jj = 0; jj < 4; jj++) acc[i][jj] = (f32x4){0.f, 0.f, 0.f, 0.f};

    int st_rl = lane >> 3;            // row within 8-row group
    int st_pc = lane & 7;             // physical chunk at dest (= lane pattern)

    // ---- loop-invariant staging sources (advance +64 u16 per staged tile)
    const u16* gA[4];
    const u16* gB[2];
#pragma unroll
    for (int ld = 0; ld < 4; ld++) {
        int row = w * 32 + ld * 8 + st_rl;
        int cg  = st_pc ^ (row & 7);
        gA[ld] = Wb + (size_t)(q0 + row) * SEQ + cg * 8;
    }
#pragma unroll
    for (int ld = 0; ld < 2; ld++) {
        int row = w * 16 + ld * 8 + st_rl;
        int cg  = st_pc ^ (row & 7);
        gB[ld] = hTb + (size_t)(e0 + row) * SEQ + cg * 8;
    }
    // ---- loop-invariant LDS dest byte offsets within a slot
    int dA[4], dB[2];
#pragma unroll
    for (int ld = 0; ld < 4; ld++) dA[ld] = (w * 32 + ld * 8) * 128 + lane * 16;
#pragma unroll
    for (int ld = 0; ld < 2; ld++) dB[ld] = 32768 + (w * 16 + ld * 8) * 128 + lane * 16;
    // ---- loop-invariant LDS read byte offsets within a slot
    int offA[8], offB[4];
#pragma unroll
    for (int ii = 0; ii < 8; ii++) {
        int ra  = wq + ii * 16 + l15;
        int pca = (kf * 4 + quad) ^ (ra & 7);
        offA[ii] = ra * 128 + pca * 16;
    }
#pragma unroll
    for (int jj = 0; jj < 4; jj++) {
        int rb  = we + jj * 16 + l15;
        int pcb = (kf * 4 + quad) ^ (rb & 7);
        offB[jj] = 32768 + rb * 128 + pcb * 16;
    }

#define STAGE_H1(si)                                                           \
    {                                                                          \
        gload_lds16(gA[0], (u16*)(smem + (si) * 49152 + dA[0]));               \
        gload_lds16(gA[1], (u16*)(smem + (si) * 49152 + dA[1]));               \
        gload_lds16(gB[0], (u16*)(smem + (si) * 49152 + dB[0]));               \
    }
#define STAGE_H2(si)                                                           \
    {                                                                          \
        gload_lds16(gA[2], (u16*)(smem + (si) * 49152 + dA[2]));               \
        gload_lds16(gA[3], (u16*)(smem + (si) * 49152 + dA[3]));               \
        gload_lds16(gB[1], (u16*)(smem + (si) * 49152 + dB[1]));               \
    }
#define ADV()                                                                  \
    {                                                                          \
        gA[0] += 64; gA[1] += 64; gA[2] += 64; gA[3] += 64;                    \
        gB[0] += 64; gB[1] += 64;                                              \
    }

#define MFMA16(i0)                                                             \
    {                                                                          \
        _Pragma("unroll")                                                      \
        for (int ii = 0; ii < 4; ii++)                                         \
            _Pragma("unroll")                                                  \
            for (int jj = 0; jj < 4; jj++)                                     \
                acc[(i0) + ii][jj] = __builtin_amdgcn_mfma_f32_16x16x32_bf16(  \
                    af[ii], bfr[jj], acc[(i0) + ii][jj], 0, 0, 0);             \
    }

    // TILE body: lockstep 2-phase, slot si (literal), staging into si2.
#define TILE(si, si2, DO_STAGE, VMC)                                           \
    {                                                                          \
        const char* Sb = smem + (si) * 49152;                                  \
        short8 af[4], bfr[4];                                                  \
        /* phase 0 */                                                          \
        _Pragma("unroll")                                                      \
        for (int ii = 0; ii < 4; ii++)                                         \
            af[ii] = *(const short8*)(Sb + offA[ii]);                          \
        _Pragma("unroll")                                                      \
        for (int jj = 0; jj < 4; jj++)                                         \
            bfr[jj] = *(const short8*)(Sb + offB[jj]);                         \
        if (DO_STAGE) STAGE_H1(si2)                                            \
        __builtin_amdgcn_s_barrier();                                          \
        asm volatile("s_waitcnt lgkmcnt(0)" ::: "memory");                     \
        __builtin_amdgcn_sched_barrier(0);                                     \
        __builtin_amdgcn_s_setprio(1);                                         \
        MFMA16(0)                                                              \
        __builtin_amdgcn_s_setprio(0);                                         \
        __builtin_amdgcn_s_barrier();                                          \
        /* phase 1 */                                                          \
        _Pragma("unroll")                                                      \
        for (int ii = 0; ii < 4; ii++)                                         \
            af[ii] = *(const short8*)(Sb + offA[4 + ii]);                      \
        if (DO_STAGE) { STAGE_H2(si2) ADV() }                                  \
        __builtin_amdgcn_s_barrier();                                          \
        asm volatile("s_waitcnt lgkmcnt(0)" ::: "memory");                     \
        __builtin_amdgcn_sched_barrier(0);                                     \
        __builtin_amdgcn_s_setprio(1);                                         \
        MFMA16(4)                                                              \
        __builtin_amdgcn_s_setprio(0);                                         \
        if ((VMC) == 6) { asm volatile("s_waitcnt vmcnt(6)" ::: "memory"); }   \
        else if ((VMC) == 0) { asm volatile("s_waitcnt vmcnt(0)" ::: "memory"); } \
        __builtin_amdgcn_s_barrier();                                          \
    }

    // Prologue: stage tiles 0 (slot 0) and 1 (slot 1).
    STAGE_H1(0) STAGE_H2(0) ADV()
    STAGE_H1(1) STAGE_H2(1) ADV()
    asm volatile("s_waitcnt vmcnt(6)" ::: "memory");   // own tile-0 loads done
    __builtin_amdgcn_s_barrier();                      // published to all

    // Tiles 0..29: unrolled x3, staging tiles 2..31, vmcnt(6) each.
    for (int g = 0; g < 10; ++g) {
        TILE(0, 2, true, 6)
        TILE(1, 0, true, 6)
        TILE(2, 1, true, 6)
    }
    // Tile 30 (slot 0): no staging; drain remaining (tile 31's 6 loads).
    TILE(0, 2, false, 0)
    // Tile 31 (slot 1): no staging, no vmcnt; end barrier guards smem reuse.
    TILE(1, 0, false, -1)
#undef TILE
#undef STAGE_H1
#undef STAGE_H2
#undef ADV
#undef MFMA16

    // Epilogue: combine kf=1 partials into kf=0 waves via ring LDS.
    // Region per wave-pair (w&3): 32KB = 32 frags x 64 lanes x 16B.
    float* red = (float*)smem;
    if (w >= 4) {
        float* reg = red + (size_t)(w & 3) * 8192;
#pragma unroll
        for (int i = 0; i < 8; i++)
#pragma unroll
            for (int jj = 0; jj < 4; jj++)
                *(f32x4*)(reg + ((i * 4 + jj) * 64 + lane) * 4) = acc[i][jj];
    }
    __syncthreads();
    if (w < 4) {
        float* reg = red + (size_t)w * 8192;
        float* outb = out + (size_t)b * SEQ * EMBED;
#pragma unroll
        for (int i = 0; i < 8; i++)
#pragma unroll
            for (int jj = 0; jj < 4; jj++) {
                f32x4 o = *(const f32x4*)(reg + ((i * 4 + jj) * 64 + lane) * 4);
                o += acc[i][jj];
#pragma unroll
                for (int r = 0; r < 4; r++)
                    outb[(size_t)(q0 + wq + i * 16 + quad * 4 + r) * EMBED
                         + e0 + we + jj * 16 + l15] = o[r];
            }
    }
}

// ---------------------------------------------------------------------------
extern "C" void kernel_launch(void* const* d_in, const int* in_sizes, int n_in,
                              void* d_out, int out_size, void* d_ws, size_t ws_size,
                              hipStream_t stream) {
    (void)in_sizes; (void)n_in; (void)out_size; (void)ws_size;
    const float* h  = (const float*)d_in[0];
    const float* Wq = (const float*)d_in[1];
    const float* bq = (const float*)d_in[2];
    const float* Wk = (const float*)d_in[3];
    const float* bk = (const float*)d_in[4];
    // d_in[5], d_in[6] (Wv, bv) are dead in the reference.
    float* out = (float*)d_out;

    char* ws = (char*)d_ws;
    u16*   Qbf  = (u16*)(ws);                                  // 1 MB
    u16*   Kbf  = (u16*)(ws + (1ull << 20));                   // 1 MB
    u16*   hT   = (u16*)(ws + (2ull << 20));                   // 16 MB
    float* lsum = (float*)(ws + (18ull << 20));                // 32 KB
    u16*   WqT  = (u16*)(ws + (18ull << 20) + (128ull << 10)); // 128 KB
    u16*   WkT  = (u16*)(ws + (18ull << 20) + (256ull << 10)); // 128 KB
    u16*   Wmat = (u16*)(ws + (19ull << 20));                  // 32 MB (total ~51 MB)

    hipLaunchKernelGGL(wt_kernel, dim3(16, 2), dim3(256), 0, stream,
                       Wq, Wk, WqT, WkT, lsum);
    hipLaunchKernelGGL(proj_kernel, dim3(512), dim3(256), 0, stream,
                       h, WqT, WkT, bq, bk, Qbf, Kbf);
    hipLaunchKernelGGL(sw_kernel, dim3(32, 4, 4), dim3(512), 0, stream,
                       Qbf, Kbf, Wmat, lsum);
    hipLaunchKernelGGL(tscale_kernel, dim3(32, 16, 4), dim3(256), 0, stream,
                       h, lsum, hT);
    hipLaunchKernelGGL(out_gemm_kernel, dim3(256), dim3(512), 0, stream,
                       Wmat, hT, out);
}